// Round 1
// baseline (878.355 us; speedup 1.0000x reference)
//
#include <hip/hip_runtime.h>
#include <hip/hip_bf16.h>
#include <stdint.h>

#define VOCAB 50257
#define NPAD  50304   // 393*128, padded N for the GEMM
#define D 768
#define E 4
#define R 32
#define B 4
#define T 512
#define NTOK (B*T)    // 2048

typedef float f32x4 __attribute__((ext_vector_type(4)));
typedef short s16x8 __attribute__((ext_vector_type(8)));

__device__ __forceinline__ void async16(const void* g, void* l) {
    __builtin_amdgcn_global_load_lds(
        (const __attribute__((address_space(1))) uint32_t*)g,
        (__attribute__((address_space(3))) uint32_t*)l, 16, 0, 0);
}

// ---------------- K1: embedding gather + routing + u = x @ W_in[e*] ----------
__global__ __launch_bounds__(256) void k_embed_route(
    const int* __restrict__ idx, const float* __restrict__ Wemb,
    const float* __restrict__ G, const float* __restrict__ Win,
    float* __restrict__ xbuf, int* __restrict__ winner, float* __restrict__ ubuf)
{
    int tok = blockIdx.x;
    int tid = threadIdx.x;
    __shared__ float xs[D];
    __shared__ float sc[E];
    __shared__ float up[8][R];

    int token = idx[tok];
    const float* wrow = Wemb + (size_t)token * D;
    float x0 = wrow[tid], x1 = wrow[tid + 256], x2 = wrow[tid + 512];
    xs[tid] = x0; xs[tid + 256] = x1; xs[tid + 512] = x2;
    float* xg = xbuf + (size_t)tok * D;
    xg[tid] = x0; xg[tid + 256] = x1; xg[tid + 512] = x2;
    __syncthreads();

    // routing scores: wave w computes expert w's dot
    int wave = tid >> 6, lane = tid & 63;
    {
        const float* g = G + wave * D;
        float p = 0.f;
        for (int d = lane; d < D; d += 64) p += xs[d] * g[d];
        for (int off = 32; off; off >>= 1) p += __shfl_down(p, off);
        if (lane == 0) sc[wave] = p;
    }
    __syncthreads();
    float s0 = sc[0], s1 = sc[1], s2 = sc[2], s3 = sc[3];
    int e = 0; float best = s0;                 // first-max (jnp.argmax) semantics
    if (s1 > best) { best = s1; e = 1; }
    if (s2 > best) { best = s2; e = 2; }
    if (s3 > best) { best = s3; e = 3; }
    if (tid == 0) winner[tok] = e;

    // u[r] = sum_d x[d] * W_in[e][d][r]; 8 d-chunks x 32 r
    int r = tid & 31, chunk = tid >> 5;
    const float* wi = Win + (size_t)e * D * R;
    float p = 0.f;
    int d0 = chunk * 96;
    for (int d = d0; d < d0 + 96; ++d) p += xs[d] * wi[d * R + r];
    up[chunk][r] = p;
    __syncthreads();
    if (tid < R) {
        float s = 0.f;
        #pragma unroll
        for (int ch = 0; ch < 8; ++ch) s += up[ch][tid];
        ubuf[(size_t)tok * R + tid] = s;
    }
}

// ---------------- K2: expert-parallel scan -----------------------------------
// The four experts' recurrent chains are independent: expert e's state only
// evolves at tokens routed to e. One block per (batch, expert) = 16 blocks,
// each compacts its token list then runs ~T/E dependent steps with u
// prefetched 2 entries ahead (covers L3/cross-XCD latency).
__global__ __launch_bounds__(64) void k_scan(
    const int* __restrict__ winner, const float* __restrict__ ubuf,
    const float* __restrict__ Wrec, float* __restrict__ cbuf)
{
    int b = blockIdx.x >> 2;
    int e = blockIdx.x & 3;
    int j = threadIdx.x;          // one wave; lanes j<32 do the math
    __shared__ float s_lds[R];
    __shared__ int   tlist[T];

    const int* wb = winner + b * T;

    // compact matching token indices via ballot + prefix popcount
    unsigned long long lanemask_lt = (j == 0) ? 0ull : (~0ull >> (64 - j));
    int base = 0;
    for (int rr = 0; rr < T / 64; ++rr) {
        int t = rr * 64 + j;
        bool match = (wb[t] == e);
        unsigned long long m = __ballot(match);
        if (match) tlist[base + __popcll(m & lanemask_lt)] = t;
        base += __popcll(m);
    }
    int total = base;             // wave-uniform

    float wr[R];                  // W_rec[e] column j in VGPRs
    if (j < R) {
        s_lds[j] = 0.f;
        #pragma unroll
        for (int i = 0; i < R; ++i) wr[i] = Wrec[(size_t)e * R * R + i * R + j];
    }
    __syncthreads();
    if (j >= R) return;

    const float* ub = ubuf + (size_t)b * T * R;
    float*       cb = cbuf + (size_t)b * T * R;

    // software pipeline: u prefetched 2 list-entries ahead
    int   t0 = 0, t1 = 0;
    float u0 = 0.f, u1 = 0.f;
    if (total > 0) { t0 = tlist[0]; u0 = ub[t0 * R + j]; }
    if (total > 1) { t1 = tlist[1]; u1 = ub[t1 * R + j]; }

    for (int k = 0; k < total; ++k) {
        int t = t0; float uj = u0;
        t0 = t1; u0 = u1;
        if (k + 2 < total) { int t2 = tlist[k + 2]; t1 = t2; u1 = ub[t2 * R + j]; }

        float a0 = uj, a1 = 0.f, a2 = 0.f, a3 = 0.f;
        #pragma unroll
        for (int q = 0; q < 8; ++q) {
            float4 sv = *(const float4*)&s_lds[q * 4];
            a0 += sv.x * wr[q * 4 + 0]; a1 += sv.y * wr[q * 4 + 1];
            a2 += sv.z * wr[q * 4 + 2]; a3 += sv.w * wr[q * 4 + 3];
        }
        float acc = (a0 + a1) + (a2 + a3);
        // tanh(x) = 1 - 2/(exp(2x)+1); stable at +/-inf with rcp
        float ex = __expf(2.f * acc);
        float th = 1.f - 2.f * __builtin_amdgcn_rcpf(ex + 1.f);
        cb[t * R + j] = th;
        s_lds[j] = th;            // program order within wave
    }
}

// ---------------- K3: y = c @ W_out[e*] + x; LayerNorm; -> bf16 h ------------
__global__ __launch_bounds__(256) void k_out_ln(
    const float* __restrict__ xbuf, const int* __restrict__ winner,
    const float* __restrict__ cbuf, const float* __restrict__ Wout,
    const float* __restrict__ gamma, const float* __restrict__ beta,
    __hip_bfloat16* __restrict__ hbuf)
{
    int tok = blockIdx.x, tid = threadIdx.x;
    __shared__ float cs[R];
    __shared__ float w1[4], w2[4];
    int e = winner[tok];
    if (tid < R) cs[tid] = cbuf[(size_t)tok * R + tid];
    __syncthreads();

    const float* wo = Wout + (size_t)e * R * D;
    const float* xg = xbuf + (size_t)tok * D;
    float y[3];
    #pragma unroll
    for (int kk = 0; kk < 3; ++kk) {
        int d = tid + kk * 256;
        float acc = xg[d];
        #pragma unroll
        for (int r = 0; r < R; ++r) acc += cs[r] * wo[r * D + d];
        y[kk] = acc;
    }
    float s1 = y[0] + y[1] + y[2];
    float s2 = y[0] * y[0] + y[1] * y[1] + y[2] * y[2];
    int wave = tid >> 6, lane = tid & 63;
    for (int off = 32; off; off >>= 1) { s1 += __shfl_down(s1, off); s2 += __shfl_down(s2, off); }
    if (lane == 0) { w1[wave] = s1; w2[wave] = s2; }
    __syncthreads();
    float m = (w1[0] + w1[1] + w1[2] + w1[3]) * (1.f / D);
    float v = (w2[0] + w2[1] + w2[2] + w2[3]) * (1.f / D) - m * m;
    float rstd = rsqrtf(v + 1e-5f);
    #pragma unroll
    for (int kk = 0; kk < 3; ++kk) {
        int d = tid + kk * 256;
        float hn = (y[kk] - m) * rstd * gamma[d] + beta[d];
        hbuf[(size_t)tok * D + d] = __float2bfloat16(hn);
    }
}

// ---------------- K4: W_emb fp32 -> bf16 (padded to NPAD rows) ---------------
__global__ __launch_bounds__(256) void k_cvt(
    const float* __restrict__ Wemb, __hip_bfloat16* __restrict__ Wb)
{
    long i = (long)(blockIdx.x * 256 + threadIdx.x) * 4;
    const long total = (long)NPAD * D;
    const long valid = (long)VOCAB * D;
    if (i >= total) return;
    float4 v;
    if (i < valid) v = *(const float4*)(Wemb + i);
    else           v = make_float4(0.f, 0.f, 0.f, 0.f);
    union { ushort4 u4; __hip_bfloat16 h[4]; } pk;
    pk.h[0] = __float2bfloat16(v.x); pk.h[1] = __float2bfloat16(v.y);
    pk.h[2] = __float2bfloat16(v.z); pk.h[3] = __float2bfloat16(v.w);
    *(ushort4*)((unsigned short*)Wb + i) = pk.u4;
}

// ---------------- K5: logits = h @ Wemb^T  (bf16 MFMA, m97 structure) --------
#define BM 128
#define BN 128
#define BK 64
#define NWG (16 * 393)            // 6288 blocks; 6288 % 8 == 0 -> simple swizzle bijective
__global__ __launch_bounds__(256) void k_gemm(
    const __hip_bfloat16* __restrict__ A,   // [2048][768]  (h)
    const __hip_bfloat16* __restrict__ Bm,  // [NPAD][768]  (W_emb bf16, B^T layout)
    float* __restrict__ Cmat)               // [2048][VOCAB]
{
    __shared__ __align__(16) char lds[BM * BK * 2 + BN * BK * 2];  // 16KB + 16KB
    const int tid = threadIdx.x;
    // XCD-aware swizzle: each XCD gets a contiguous chunk of wgids; within a
    // chunk M varies fastest, so the 16 blocks sharing a B-panel (same n0)
    // land on ONE XCD's L2 instead of being spread across all 8.
    const int orig = blockIdx.x;
    const int wg = (orig & 7) * (NWG / 8) + (orig >> 3);
    const int m0 = (wg & 15) * BM;
    const int n0 = (wg >> 4) * BN;
    const int wave = tid >> 6, lane = tid & 63;
    const int wm = (wave >> 1) * 64, wn = (wave & 1) * 64;
    const int l15 = lane & 15, quad = lane >> 4;

    f32x4 acc[4][4] = {};

    const int srow = tid >> 3;             // 0..31 (+32 per round)
    const int skel = (tid & 7) * 8;        // k element offset within BK
    const size_t aBase = (size_t)(m0 + srow) * 768 + skel;
    const size_t bBase = (size_t)(n0 + srow) * 768 + skel;
    char* aT = lds;
    char* bT = lds + BM * BK * 2;
    const int ldsOff = tid * 16;

    for (int k0 = 0; k0 < 768; k0 += BK) {
        #pragma unroll
        for (int rr = 0; rr < 4; ++rr) {
            async16(A  + aBase + (size_t)rr * 32 * 768 + k0, aT + rr * 4096 + ldsOff);
            async16(Bm + bBase + (size_t)rr * 32 * 768 + k0, bT + rr * 4096 + ldsOff);
        }
        __syncthreads();
        #pragma unroll
        for (int kk = 0; kk < BK; kk += 32) {
            s16x8 af[4], bf[4];
            #pragma unroll
            for (int i = 0; i < 4; ++i)
                af[i] = *(const s16x8*)(aT + ((wm + i * 16 + l15) * BK + kk + quad * 8) * 2);
            #pragma unroll
            for (int j = 0; j < 4; ++j)
                bf[j] = *(const s16x8*)(bT + ((wn + j * 16 + l15) * BK + kk + quad * 8) * 2);
            #pragma unroll
            for (int i = 0; i < 4; ++i)
                #pragma unroll
                for (int j = 0; j < 4; ++j)
                    acc[i][j] = __builtin_amdgcn_mfma_f32_16x16x32_bf16(af[i], bf[j], acc[i][j], 0, 0, 0);
        }
        __syncthreads();
    }

    // epilogue: C/D layout col=lane&15, row=quad*4+reg (m89/m91-verified)
    #pragma unroll
    for (int i = 0; i < 4; ++i) {
        #pragma unroll
        for (int j = 0; j < 4; ++j) {
            int col = n0 + wn + j * 16 + l15;
            if (col < VOCAB) {
                #pragma unroll
                for (int r = 0; r < 4; ++r) {
                    int row = m0 + wm + i * 16 + quad * 4 + r;
                    Cmat[(size_t)row * VOCAB + col] = acc[i][j][r];
                }
            }
        }
    }
}

extern "C" void kernel_launch(void* const* d_in, const int* in_sizes, int n_in,
                              void* d_out, int out_size, void* d_ws, size_t ws_size,
                              hipStream_t stream)
{
    const int*   idx   = (const int*)d_in[0];
    const float* Wemb  = (const float*)d_in[1];
    const float* G     = (const float*)d_in[2];
    const float* Win   = (const float*)d_in[3];
    const float* Wrec  = (const float*)d_in[4];
    const float* Wout  = (const float*)d_in[5];
    const float* gamma = (const float*)d_in[6];
    const float* beta  = (const float*)d_in[7];
    float* out = (float*)d_out;

    char* ws = (char*)d_ws;
    float*          xbuf   = (float*)(ws);                    // 6,291,456 B
    int*            winner = (int*)  (ws + 6291456);          // 8,192 B
    float*          ubuf   = (float*)(ws + 6299648);          // 262,144 B
    float*          cbuf   = (float*)(ws + 6561792);          // 262,144 B
    __hip_bfloat16* hbuf   = (__hip_bfloat16*)(ws + 6823936); // 3,145,728 B
    __hip_bfloat16* wembb  = (__hip_bfloat16*)(ws + 9969664); // 77,266,944 B (total ~87.2 MB)

    k_cvt<<<(NPAD * D / 4 + 255) / 256, 256, 0, stream>>>(Wemb, wembb);
    k_embed_route<<<NTOK, 256, 0, stream>>>(idx, Wemb, G, Win, xbuf, winner, ubuf);
    k_scan<<<B * E, 64, 0, stream>>>(winner, ubuf, Wrec, cbuf);
    k_out_ln<<<NTOK, 256, 0, stream>>>(xbuf, winner, cbuf, Wout, gamma, beta, hbuf);
    k_gemm<<<NWG, 256, 0, stream>>>(hbuf, wembb, out);
}

// Round 2
// 789.011 us; speedup vs baseline: 1.1132x; 1.1132x over previous
//
#include <hip/hip_runtime.h>
#include <hip/hip_bf16.h>
#include <stdint.h>

#define VOCAB 50257
#define NPAD  50432   // 197*256, padded N for the 256-wide GEMM tiles
#define D 768
#define E 4
#define R 32
#define B 4
#define T 512
#define NTOK (B*T)    // 2048

typedef float f32x4 __attribute__((ext_vector_type(4)));
typedef short s16x8 __attribute__((ext_vector_type(8)));

__device__ __forceinline__ void async16(const void* g, void* l) {
    __builtin_amdgcn_global_load_lds(
        (const __attribute__((address_space(1))) uint32_t*)g,
        (__attribute__((address_space(3))) uint32_t*)l, 16, 0, 0);
}

// ---------------- K1: embedding gather + routing + u = x @ W_in[e*] ----------
__global__ __launch_bounds__(256) void k_embed_route(
    const int* __restrict__ idx, const float* __restrict__ Wemb,
    const float* __restrict__ G, const float* __restrict__ Win,
    float* __restrict__ xbuf, int* __restrict__ winner, float* __restrict__ ubuf)
{
    int tok = blockIdx.x;
    int tid = threadIdx.x;
    __shared__ float xs[D];
    __shared__ float sc[E];
    __shared__ float up[8][R];

    int token = idx[tok];
    const float* wrow = Wemb + (size_t)token * D;
    float x0 = wrow[tid], x1 = wrow[tid + 256], x2 = wrow[tid + 512];
    xs[tid] = x0; xs[tid + 256] = x1; xs[tid + 512] = x2;
    float* xg = xbuf + (size_t)tok * D;
    xg[tid] = x0; xg[tid + 256] = x1; xg[tid + 512] = x2;
    __syncthreads();

    int wave = tid >> 6, lane = tid & 63;
    {
        const float* g = G + wave * D;
        float p = 0.f;
        for (int d = lane; d < D; d += 64) p += xs[d] * g[d];
        for (int off = 32; off; off >>= 1) p += __shfl_down(p, off);
        if (lane == 0) sc[wave] = p;
    }
    __syncthreads();
    float s0 = sc[0], s1 = sc[1], s2 = sc[2], s3 = sc[3];
    int e = 0; float best = s0;                 // first-max (jnp.argmax) semantics
    if (s1 > best) { best = s1; e = 1; }
    if (s2 > best) { best = s2; e = 2; }
    if (s3 > best) { best = s3; e = 3; }
    if (tid == 0) winner[tok] = e;

    int r = tid & 31, chunk = tid >> 5;
    const float* wi = Win + (size_t)e * D * R;
    float p = 0.f;
    int d0 = chunk * 96;
    for (int d = d0; d < d0 + 96; ++d) p += xs[d] * wi[d * R + r];
    up[chunk][r] = p;
    __syncthreads();
    if (tid < R) {
        float s = 0.f;
        #pragma unroll
        for (int ch = 0; ch < 8; ++ch) s += up[ch][tid];
        ubuf[(size_t)tok * R + tid] = s;
    }
}

// ---------------- K2: expert-parallel scan -----------------------------------
__global__ __launch_bounds__(64) void k_scan(
    const int* __restrict__ winner, const float* __restrict__ ubuf,
    const float* __restrict__ Wrec, float* __restrict__ cbuf)
{
    int b = blockIdx.x >> 2;
    int e = blockIdx.x & 3;
    int j = threadIdx.x;
    __shared__ float s_lds[R];
    __shared__ int   tlist[T];

    const int* wb = winner + b * T;

    unsigned long long lanemask_lt = (j == 0) ? 0ull : (~0ull >> (64 - j));
    int base = 0;
    for (int rr = 0; rr < T / 64; ++rr) {
        int t = rr * 64 + j;
        bool match = (wb[t] == e);
        unsigned long long m = __ballot(match);
        if (match) tlist[base + __popcll(m & lanemask_lt)] = t;
        base += __popcll(m);
    }
    int total = base;

    float wr[R];
    if (j < R) {
        s_lds[j] = 0.f;
        #pragma unroll
        for (int i = 0; i < R; ++i) wr[i] = Wrec[(size_t)e * R * R + i * R + j];
    }
    __syncthreads();
    if (j >= R) return;

    const float* ub = ubuf + (size_t)b * T * R;
    float*       cb = cbuf + (size_t)b * T * R;

    int   t0 = 0, t1 = 0;
    float u0 = 0.f, u1 = 0.f;
    if (total > 0) { t0 = tlist[0]; u0 = ub[t0 * R + j]; }
    if (total > 1) { t1 = tlist[1]; u1 = ub[t1 * R + j]; }

    for (int k = 0; k < total; ++k) {
        int t = t0; float uj = u0;
        t0 = t1; u0 = u1;
        if (k + 2 < total) { int t2 = tlist[k + 2]; t1 = t2; u1 = ub[t2 * R + j]; }

        float a0 = uj, a1 = 0.f, a2 = 0.f, a3 = 0.f;
        #pragma unroll
        for (int q = 0; q < 8; ++q) {
            float4 sv = *(const float4*)&s_lds[q * 4];
            a0 += sv.x * wr[q * 4 + 0]; a1 += sv.y * wr[q * 4 + 1];
            a2 += sv.z * wr[q * 4 + 2]; a3 += sv.w * wr[q * 4 + 3];
        }
        float acc = (a0 + a1) + (a2 + a3);
        float ex = __expf(2.f * acc);
        float th = 1.f - 2.f * __builtin_amdgcn_rcpf(ex + 1.f);
        cb[t * R + j] = th;
        s_lds[j] = th;
    }
}

// ---------------- K3: y = c @ W_out[e*] + x; LayerNorm; -> bf16 h ------------
__global__ __launch_bounds__(256) void k_out_ln(
    const float* __restrict__ xbuf, const int* __restrict__ winner,
    const float* __restrict__ cbuf, const float* __restrict__ Wout,
    const float* __restrict__ gamma, const float* __restrict__ beta,
    __hip_bfloat16* __restrict__ hbuf)
{
    int tok = blockIdx.x, tid = threadIdx.x;
    __shared__ float cs[R];
    __shared__ float w1[4], w2[4];
    int e = winner[tok];
    if (tid < R) cs[tid] = cbuf[(size_t)tok * R + tid];
    __syncthreads();

    const float* wo = Wout + (size_t)e * R * D;
    const float* xg = xbuf + (size_t)tok * D;
    float y[3];
    #pragma unroll
    for (int kk = 0; kk < 3; ++kk) {
        int d = tid + kk * 256;
        float acc = xg[d];
        #pragma unroll
        for (int r = 0; r < R; ++r) acc += cs[r] * wo[r * D + d];
        y[kk] = acc;
    }
    float s1 = y[0] + y[1] + y[2];
    float s2 = y[0] * y[0] + y[1] * y[1] + y[2] * y[2];
    int wave = tid >> 6, lane = tid & 63;
    for (int off = 32; off; off >>= 1) { s1 += __shfl_down(s1, off); s2 += __shfl_down(s2, off); }
    if (lane == 0) { w1[wave] = s1; w2[wave] = s2; }
    __syncthreads();
    float m = (w1[0] + w1[1] + w1[2] + w1[3]) * (1.f / D);
    float v = (w2[0] + w2[1] + w2[2] + w2[3]) * (1.f / D) - m * m;
    float rstd = rsqrtf(v + 1e-5f);
    #pragma unroll
    for (int kk = 0; kk < 3; ++kk) {
        int d = tid + kk * 256;
        float hn = (y[kk] - m) * rstd * gamma[d] + beta[d];
        hbuf[(size_t)tok * D + d] = __float2bfloat16(hn);
    }
}

// ---------------- K4: W_emb fp32 -> bf16 (padded to NPAD rows) ---------------
__global__ __launch_bounds__(256) void k_cvt(
    const float* __restrict__ Wemb, __hip_bfloat16* __restrict__ Wb)
{
    long i = (long)(blockIdx.x * 256 + threadIdx.x) * 4;
    const long total = (long)NPAD * D;
    const long valid = (long)VOCAB * D;
    if (i >= total) return;
    float4 v;
    if (i < valid) v = *(const float4*)(Wemb + i);
    else           v = make_float4(0.f, 0.f, 0.f, 0.f);
    union { ushort4 u4; __hip_bfloat16 h[4]; } pk;
    pk.h[0] = __float2bfloat16(v.x); pk.h[1] = __float2bfloat16(v.y);
    pk.h[2] = __float2bfloat16(v.z); pk.h[3] = __float2bfloat16(v.w);
    *(ushort4*)((unsigned short*)Wb + i) = pk.u4;
}

// ---------------- K5: logits = h @ Wemb^T -----------------------------------
// 256x256 tile, BK=64, 8 waves, double-buffered LDS (128 KiB), 4 phases per
// K-tile with counted vmcnt (never 0 in main loop): while computing tile t,
// each phase issues one 16KB chunk of tile t+1 (order A-k[0:32) B-k[0:32)
// A-k[32:64) B-k[32:64)); vmcnt(4) before the phase-1/phase-3 barriers proves
// (in-order counting) that exactly the chunks needed next have landed.
// LDS per buffer: A = 2 kk-halves x [256][32] bf16 (32KB), B same. XOR
// swizzle byte^=((row&3)<<4) applied on BOTH sides: pre-swizzled global source
// (global_load_lds dest stays linear) + swizzled ds_read address.
#define BM 256
#define BN 256
#define BK 64
#define MB (NTOK / BM)        // 8
#define NB (NPAD / BN)        // 197
#define NWG (MB * NB)         // 1576; % 8 == 0 -> simple XCD swizzle bijective
__global__ __launch_bounds__(512, 2) void k_gemm(
    const __hip_bfloat16* __restrict__ A,   // [2048][768]  (h)
    const __hip_bfloat16* __restrict__ Bm,  // [NPAD][768]  (W_emb bf16, B^T layout)
    float* __restrict__ Cmat)               // [2048][VOCAB]
{
    __shared__ __align__(16) char lds[131072];   // 2 x (A 32KB + B 32KB)
    const int tid = threadIdx.x;
    const int orig = blockIdx.x;
    const int wg = (orig & 7) * (NWG / 8) + (orig >> 3);   // XCD-contiguous chunks
    const int m0 = (wg & (MB - 1)) * BM;                   // M fastest in chunk
    const int n0 = (wg / MB) * BN;
    const int wave = tid >> 6, lane = tid & 63;
    const int wm = (wave & 1) * 128;        // 2 M-halves
    const int wn = (wave >> 1) * 64;        // 4 N-quarters
    const int l15 = lane & 15, quad = lane >> 4;

    f32x4 acc[8][4] = {};

    // staging thread map: row_l = rr*128 + (tid>>2), 16B col-chunk = tid&3.
    // source pre-swizzle: src k-chunk = (tid&3) ^ (row_l&3)
    const int srowS = tid >> 2;                                  // 0..127
    const int skelS = (((tid & 3) ^ ((tid >> 2) & 3)) * 8);      // elems in 32-k half
    const size_t aBase = (size_t)(m0 + srowS) * 768 + skelS;
    const size_t bBase = (size_t)(n0 + srowS) * 768 + skelS;
    const int ldsPos = tid * 16;

    // buffer layout: buf*65536 + {A h0:0, A h1:16K, B h0:32K, B h1:48K}
    auto stageA = [&](char* buf, int kg, int h) {
        async16(A + aBase + kg + h * 32,                      buf + h * 16384 + ldsPos);
        async16(A + aBase + (size_t)128 * 768 + kg + h * 32,  buf + h * 16384 + 8192 + ldsPos);
    };
    auto stageB = [&](char* buf, int kg, int h) {
        async16(Bm + bBase + kg + h * 32,                     buf + 32768 + h * 16384 + ldsPos);
        async16(Bm + bBase + (size_t)128 * 768 + kg + h * 32, buf + 32768 + h * 16384 + 8192 + ldsPos);
    };

    const int swz = ((quad ^ (l15 & 3)) << 4);   // row&3 == l15&3 for all frags

    // prologue: stage tile 0 chunks in order A0,B0,A1,B1 (8 loads/thread out)
    stageA(lds, 0, 0); stageB(lds, 0, 0); stageA(lds, 0, 1); stageB(lds, 0, 1);

    for (int t = 0; t < 12; ++t) {
        char* bufC = lds + (t & 1) * 65536;
        char* bufN = lds + ((t + 1) & 1) * 65536;
        const int k1 = (t + 1) * BK;
        const bool pre = (t < 11);
        s16x8 af[8], bfr[2];

        // ---- phase 1: kk-half 0, j=0,1 ----
        asm volatile("s_waitcnt vmcnt(4)" ::: "memory");   // A0(t),B0(t) landed
        __builtin_amdgcn_s_barrier();
        __builtin_amdgcn_sched_barrier(0);
        if (pre) stageA(bufN, k1, 0);
        #pragma unroll
        for (int i = 0; i < 8; ++i)
            af[i] = *(const s16x8*)(bufC + (wm + i * 16 + l15) * 64 + swz);
        #pragma unroll
        for (int j = 0; j < 2; ++j)
            bfr[j] = *(const s16x8*)(bufC + 32768 + (wn + j * 16 + l15) * 64 + swz);
        __builtin_amdgcn_s_setprio(1);
        #pragma unroll
        for (int i = 0; i < 8; ++i) {
            acc[i][0] = __builtin_amdgcn_mfma_f32_16x16x32_bf16(af[i], bfr[0], acc[i][0], 0, 0, 0);
            acc[i][1] = __builtin_amdgcn_mfma_f32_16x16x32_bf16(af[i], bfr[1], acc[i][1], 0, 0, 0);
        }
        __builtin_amdgcn_s_setprio(0);

        // ---- phase 2: kk-half 0, j=2,3 ----
        __builtin_amdgcn_s_barrier();
        __builtin_amdgcn_sched_barrier(0);
        if (pre) stageB(bufN, k1, 0);
        #pragma unroll
        for (int j = 0; j < 2; ++j)
            bfr[j] = *(const s16x8*)(bufC + 32768 + (wn + (j + 2) * 16 + l15) * 64 + swz);
        __builtin_amdgcn_s_setprio(1);
        #pragma unroll
        for (int i = 0; i < 8; ++i) {
            acc[i][2] = __builtin_amdgcn_mfma_f32_16x16x32_bf16(af[i], bfr[0], acc[i][2], 0, 0, 0);
            acc[i][3] = __builtin_amdgcn_mfma_f32_16x16x32_bf16(af[i], bfr[1], acc[i][3], 0, 0, 0);
        }
        __builtin_amdgcn_s_setprio(0);

        // ---- phase 3: kk-half 1, j=0,1 ----
        if (t == 11) asm volatile("s_waitcnt vmcnt(0)" ::: "memory");  // tail drain
        else         asm volatile("s_waitcnt vmcnt(4)" ::: "memory"); // A1(t),B1(t) landed
        __builtin_amdgcn_s_barrier();
        __builtin_amdgcn_sched_barrier(0);
        if (pre) stageA(bufN, k1, 1);
        #pragma unroll
        for (int i = 0; i < 8; ++i)
            af[i] = *(const s16x8*)(bufC + 16384 + (wm + i * 16 + l15) * 64 + swz);
        #pragma unroll
        for (int j = 0; j < 2; ++j)
            bfr[j] = *(const s16x8*)(bufC + 49152 + (wn + j * 16 + l15) * 64 + swz);
        __builtin_amdgcn_s_setprio(1);
        #pragma unroll
        for (int i = 0; i < 8; ++i) {
            acc[i][0] = __builtin_amdgcn_mfma_f32_16x16x32_bf16(af[i], bfr[0], acc[i][0], 0, 0, 0);
            acc[i][1] = __builtin_amdgcn_mfma_f32_16x16x32_bf16(af[i], bfr[1], acc[i][1], 0, 0, 0);
        }
        __builtin_amdgcn_s_setprio(0);

        // ---- phase 4: kk-half 1, j=2,3 ----
        __builtin_amdgcn_s_barrier();
        __builtin_amdgcn_sched_barrier(0);
        if (pre) stageB(bufN, k1, 1);
        #pragma unroll
        for (int j = 0; j < 2; ++j)
            bfr[j] = *(const s16x8*)(bufC + 49152 + (wn + (j + 2) * 16 + l15) * 64 + swz);
        __builtin_amdgcn_s_setprio(1);
        #pragma unroll
        for (int i = 0; i < 8; ++i) {
            acc[i][2] = __builtin_amdgcn_mfma_f32_16x16x32_bf16(af[i], bfr[0], acc[i][2], 0, 0, 0);
            acc[i][3] = __builtin_amdgcn_mfma_f32_16x16x32_bf16(af[i], bfr[1], acc[i][3], 0, 0, 0);
        }
        __builtin_amdgcn_s_setprio(0);
    }

    // epilogue: C/D layout col=lane&15, row=quad*4+reg (m89/m91-verified)
    #pragma unroll
    for (int i = 0; i < 8; ++i) {
        #pragma unroll
        for (int j = 0; j < 4; ++j) {
            int col = n0 + wn + j * 16 + l15;
            if (col < VOCAB) {
                #pragma unroll
                for (int r = 0; r < 4; ++r) {
                    int row = m0 + wm + i * 16 + quad * 4 + r;
                    Cmat[(size_t)row * VOCAB + col] = acc[i][j][r];
                }
            }
        }
    }
}

extern "C" void kernel_launch(void* const* d_in, const int* in_sizes, int n_in,
                              void* d_out, int out_size, void* d_ws, size_t ws_size,
                              hipStream_t stream)
{
    const int*   idx   = (const int*)d_in[0];
    const float* Wemb  = (const float*)d_in[1];
    const float* G     = (const float*)d_in[2];
    const float* Win   = (const float*)d_in[3];
    const float* Wrec  = (const float*)d_in[4];
    const float* Wout  = (const float*)d_in[5];
    const float* gamma = (const float*)d_in[6];
    const float* beta  = (const float*)d_in[7];
    float* out = (float*)d_out;

    char* ws = (char*)d_ws;
    float*          xbuf   = (float*)(ws);                    // 6,291,456 B
    int*            winner = (int*)  (ws + 6291456);          // 8,192 B
    float*          ubuf   = (float*)(ws + 6299648);          // 262,144 B
    float*          cbuf   = (float*)(ws + 6561792);          // 262,144 B
    __hip_bfloat16* hbuf   = (__hip_bfloat16*)(ws + 6823936); // 3,145,728 B
    __hip_bfloat16* wembb  = (__hip_bfloat16*)(ws + 9969664); // 77,463,552 B (total ~87.4 MB)

    k_cvt<<<(NPAD * D / 4 + 255) / 256, 256, 0, stream>>>(Wemb, wembb);
    k_embed_route<<<NTOK, 256, 0, stream>>>(idx, Wemb, G, Win, xbuf, winner, ubuf);
    k_scan<<<B * E, 64, 0, stream>>>(winner, ubuf, Wrec, cbuf);
    k_out_ln<<<NTOK, 256, 0, stream>>>(xbuf, winner, cbuf, Wout, gamma, beta, hbuf);
    k_gemm<<<NWG, 512, 0, stream>>>(hbuf, wembb, out);
}